// Round 3
// baseline (1538.090 us; speedup 1.0000x reference)
//
#include <hip/hip_runtime.h>
#include <cstdint>
#include <cstddef>

// ---------- types ----------
typedef _Float16 half2v __attribute__((ext_vector_type(2)));
typedef _Float16 half4v __attribute__((ext_vector_type(4)));
typedef _Float16 half8v __attribute__((ext_vector_type(8)));
typedef float f32x4 __attribute__((ext_vector_type(4)));

#if __has_builtin(__builtin_amdgcn_fdot2)
#define FDOT2(a, b, c) __builtin_amdgcn_fdot2((a), (b), (c), false)
#else
static __device__ __forceinline__ float fdot2_fb(half2v a, half2v b, float c) {
    return c + (float)a[0] * (float)b[0] + (float)a[1] * (float)b[1];
}
#define FDOT2(a, b, c) fdot2_fb((a), (b), (c))
#endif

#define SV2(v, i0, i1) __builtin_shufflevector((v), (v), (i0), (i1))

__device__ __forceinline__ float sigm(float x) { return 1.0f / (1.0f + __expf(-x)); }
__device__ __forceinline__ float tanh_(float x) { return 1.0f - 2.0f / (__expf(2.0f * x) + 1.0f); }

// Problem constants
#define BB 128
#define TT 512
#define II 300
#define IIP 320   // padded K for fp16 path
#define HH 256
#define GG 1024  // 4*H

// ============================================================================
// Kernel 0: convert X (65536x300 f32) and W_ih_f (1024x300 f32) to fp16 with
// zero-padded K=320 rows, enabling 16B-aligned global_load_lds in the GEMM.
// ============================================================================
__global__ __launch_bounds__(256) void cvt_xw(
    const float* __restrict__ X, const float* __restrict__ W,
    _Float16* __restrict__ Xh, _Float16* __restrict__ Wh)
{
    const int total = (65536 + 1024) * 40;   // 8-elem chunks per padded row
    for (int c = blockIdx.x * 256 + threadIdx.x; c < total; c += gridDim.x * 256) {
        const int row = c / 40;
        const int ch = c - row * 40;
        const int k0 = ch * 8;
        const float* src;
        _Float16* dst;
        if (row < 65536) {
            src = X + (size_t)row * II;
            dst = Xh + (size_t)row * IIP;
        } else {
            src = W + (size_t)(row - 65536) * II;
            dst = Wh + (size_t)(row - 65536) * IIP;
        }
        half8v hv;
        if (k0 + 8 <= II) {
            float4 a = *(const float4*)(src + k0);
            float4 b = *(const float4*)(src + k0 + 4);
            hv = half8v{(_Float16)a.x, (_Float16)a.y, (_Float16)a.z, (_Float16)a.w,
                        (_Float16)b.x, (_Float16)b.y, (_Float16)b.z, (_Float16)b.w};
        } else {
#pragma unroll
            for (int q = 0; q < 8; ++q) {
                const int k = k0 + q;
                hv[q] = (k < II) ? (_Float16)src[k] : (_Float16)0.f;
            }
        }
        *(half8v*)(dst + k0) = hv;
    }
}

// ============================================================================
// Kernel 1b: xp GEMM, fp16 inputs via global_load_lds (m97 structure).
// XP[m][n] = sum_k Xh[m][k]*Wh[n][k] + bias[n].  M=65536, N=1024, K=320.
// ============================================================================
#if __has_builtin(__builtin_amdgcn_global_load_lds)
#define HAVE_GLL 1
__device__ __forceinline__ void gll16(const _Float16* g, _Float16* l) {
    __builtin_amdgcn_global_load_lds(
        (const __attribute__((address_space(1))) void*)g,
        (__attribute__((address_space(3))) void*)l, 16, 0, 0);
}
#else
#define HAVE_GLL 0
#endif

__global__ __launch_bounds__(256) void gemm_xp_h(
    const _Float16* __restrict__ Xh, const _Float16* __restrict__ Wh,
    const float* __restrict__ bias, _Float16* __restrict__ XP)
{
    __shared__ __align__(16) _Float16 As[128 * 32];
    __shared__ __align__(16) _Float16 Bs[128 * 32];

    const int t = threadIdx.x;
    const int m0 = blockIdx.y * 128;
    const int n0 = blockIdx.x * 128;
    const int lane = t & 63;
    const int wv = t >> 6;
    const int mq = (wv >> 1) * 4;
    const int nq = (wv & 1) * 4;

    // staging chunk decode (two rounds per tile; c is lane-linear per round)
    int rowd[2], k4d[2], cidx[2];
#pragma unroll
    for (int r = 0; r < 2; ++r) {
        const int c = wv * 128 + r * 64 + lane;
        cidx[r] = c;
        rowd[r] = ((c >> 6) << 4) | (c & 15);
        k4d[r] = (c >> 4) & 3;
    }

    f32x4 acc[4][4];
#pragma unroll
    for (int i = 0; i < 4; ++i)
#pragma unroll
        for (int j = 0; j < 4; ++j) acc[i][j] = f32x4{0.f, 0.f, 0.f, 0.f};

    for (int kc = 0; kc < IIP; kc += 32) {
        __syncthreads();
#pragma unroll
        for (int r = 0; r < 2; ++r) {
            const _Float16* ga = Xh + (size_t)(m0 + rowd[r]) * IIP + kc + k4d[r] * 8;
            const _Float16* gb = Wh + (size_t)(n0 + rowd[r]) * IIP + kc + k4d[r] * 8;
#if HAVE_GLL
            gll16(ga, &As[cidx[r] * 8]);
            gll16(gb, &Bs[cidx[r] * 8]);
#else
            *(half8v*)(&As[cidx[r] * 8]) = *(const half8v*)ga;
            *(half8v*)(&Bs[cidx[r] * 8]) = *(const half8v*)gb;
#endif
        }
        __syncthreads();

        half8v af[4], bf[4];
#pragma unroll
        for (int i = 0; i < 4; ++i) {
            af[i] = *(const half8v*)(&As[(mq + i) * 512 + (lane >> 4) * 128 + (lane & 15) * 8]);
            bf[i] = *(const half8v*)(&Bs[(nq + i) * 512 + (lane >> 4) * 128 + (lane & 15) * 8]);
        }
#pragma unroll
        for (int i = 0; i < 4; ++i)
#pragma unroll
            for (int j = 0; j < 4; ++j)
                acc[i][j] = __builtin_amdgcn_mfma_f32_16x16x32_f16(af[i], bf[j], acc[i][j], 0, 0, 0);
    }

#pragma unroll
    for (int j = 0; j < 4; ++j) {
        const int n = n0 + (nq + j) * 16 + (lane & 15);
        const float bv = bias[n];
#pragma unroll
        for (int i = 0; i < 4; ++i) {
#pragma unroll
            for (int r = 0; r < 4; ++r) {
                const int m = m0 + (mq + i) * 16 + (lane >> 4) * 4 + r;
                XP[(size_t)m * GG + n] = (_Float16)(acc[i][j][r] + bv);
            }
        }
    }
}

// ============================================================================
// Kernel 1 (fallback): xp GEMM from f32 inputs (the proven v1 kernel).
// ============================================================================
__global__ __launch_bounds__(256, 3) void gemm_xp(
    const float* __restrict__ X, const float* __restrict__ W,
    const float* __restrict__ bias, _Float16* __restrict__ XP)
{
    __shared__ _Float16 As[128 * 32];
    __shared__ _Float16 Bs[128 * 32];

    const int t = threadIdx.x;
    const int m0 = blockIdx.y * 128;
    const int n0 = blockIdx.x * 128;
    const int kpos = t & 7;
    const int rbase = t >> 3;
    const int lane = t & 63;
    const int wv = t >> 6;
    const int mq = (wv >> 1) * 4;
    const int nq = (wv & 1) * 4;

    f32x4 acc[4][4];
#pragma unroll
    for (int i = 0; i < 4; ++i)
#pragma unroll
        for (int j = 0; j < 4; ++j) acc[i][j] = f32x4{0.f, 0.f, 0.f, 0.f};

    for (int kc = 0; kc < 320; kc += 32) {
        __syncthreads();
        const int k0 = kc + kpos * 4;
#pragma unroll
        for (int rr = 0; rr < 4; ++rr) {
            const int row = rbase + rr * 32;
            float4 va = {0.f, 0.f, 0.f, 0.f}, vb = {0.f, 0.f, 0.f, 0.f};
            if (k0 < 300) {
                va = *(const float4*)(X + (size_t)(m0 + row) * II + k0);
                vb = *(const float4*)(W + (size_t)(n0 + row) * II + k0);
            }
            const int idx = (row >> 4) * 512 + (kpos >> 1) * 128 + (row & 15) * 8 + (kpos & 1) * 4;
            half4v ha = {(_Float16)va.x, (_Float16)va.y, (_Float16)va.z, (_Float16)va.w};
            half4v hb = {(_Float16)vb.x, (_Float16)vb.y, (_Float16)vb.z, (_Float16)vb.w};
            *(half4v*)(&As[idx]) = ha;
            *(half4v*)(&Bs[idx]) = hb;
        }
        __syncthreads();

        half8v af[4], bf[4];
#pragma unroll
        for (int i = 0; i < 4; ++i) {
            af[i] = *(const half8v*)(&As[(mq + i) * 512 + (lane >> 4) * 128 + (lane & 15) * 8]);
            bf[i] = *(const half8v*)(&Bs[(nq + i) * 512 + (lane >> 4) * 128 + (lane & 15) * 8]);
        }
#pragma unroll
        for (int i = 0; i < 4; ++i)
#pragma unroll
            for (int j = 0; j < 4; ++j)
                acc[i][j] = __builtin_amdgcn_mfma_f32_16x16x32_f16(af[i], bf[j], acc[i][j], 0, 0, 0);
    }

#pragma unroll
    for (int j = 0; j < 4; ++j) {
        const int n = n0 + (nq + j) * 16 + (lane & 15);
        const float bv = bias[n];
#pragma unroll
        for (int i = 0; i < 4; ++i) {
#pragma unroll
            for (int r = 0; r < 4; ++r) {
                const int m = m0 + (mq + i) * 16 + (lane >> 4) * 4 + r;
                XP[(size_t)m * GG + n] = (_Float16)(acc[i][j][r] + bv);
            }
        }
    }
}

// ============================================================================
// Kernel 2: forward recurrence, v3: 1024 threads/block (16 waves = 4/SIMD)
// for 2x the latency hiding of v1's 8-wave config (v1 counters: VALUBusy 35%,
// LDS ~40%, no pipe saturated => latency-bound in barrier lockstep).
//
// Mapping: lane l of wave wv: gate = l>>4 (0=i,1=f,2=g,3=o), j = wv*16+(l&15),
// row = gate*256 + j. Each thread owns ONE Whh row (256 ks):
//   ks [0,192)   resident in 96 VGPRs (half2) — 128-reg budget @4 waves/SIMD
//   ks [192,256) in 128 KB LDS, 8 b128 reads/step (own row, distinct addr)
// h(t-1) read as 32 b128 broadcasts from 1 KB ping-pong buffer.
// Gate combine: 3 independent shfl_xor (16/32/48) + 8 cndmask selects; every
// lane computes c,h redundantly (4x); gate==0 lanes publish h. ONE barrier
// per step, same as v1.
// ============================================================================
__global__ __attribute__((amdgpu_flat_work_group_size(1024, 1024), amdgpu_waves_per_eu(4, 4)))
void lstm_fwd(
    const float* __restrict__ Whh, const _Float16* __restrict__ XP,
    float* __restrict__ HF)
{
    __shared__ _Float16 wlds[8 * 1024 * 8];          // 128 KB: [grp][row][8]
    __shared__ __align__(16) _Float16 hlds[2][HH];   // 1 KB ping-pong

    const int t = threadIdx.x;
    const int b = blockIdx.x;
    const int l = t & 63;
    const int wv = t >> 6;
    const int gate = l >> 4;               // 0:i 1:f 2:g 3:o
    const int j = wv * 16 + (l & 15);      // 0..255
    const int row = gate * 256 + j;        // Whh row this thread owns
    const bool gb0 = (gate & 1) != 0;
    const bool gb1 = (gate & 2) != 0;

    // ---- resident weights: k = 0..191 (96 VGPRs of half2) ----
    half2v w[96];
    {
        const float* wr = Whh + (size_t)row * HH;
#pragma unroll
        for (int i = 0; i < 48; ++i) {
            float4 v = *(const float4*)(wr + i * 4);
            w[2 * i]     = half2v{(_Float16)v.x, (_Float16)v.y};
            w[2 * i + 1] = half2v{(_Float16)v.z, (_Float16)v.w};
        }
    }
    // ---- LDS weights: k = 192..255; thread t fills row t (bijective) ----
#pragma unroll
    for (int grp = 0; grp < 8; ++grp) {
        float4 a  = *(const float4*)(Whh + (size_t)t * HH + 192 + grp * 8);
        float4 c4 = *(const float4*)(Whh + (size_t)t * HH + 192 + grp * 8 + 4);
        half8v hv = {(_Float16)a.x, (_Float16)a.y, (_Float16)a.z, (_Float16)a.w,
                     (_Float16)c4.x, (_Float16)c4.y, (_Float16)c4.z, (_Float16)c4.w};
        *(half8v*)(&wlds[grp * 8192 + t * 8]) = hv;
    }
    if (t < HH) hlds[0][t] = (_Float16)0.f;
    float c = 0.0f;
    __syncthreads();

    const _Float16* xq = XP + (size_t)b * TT * GG + row;
    _Float16 x = *xq;

    for (int ts = 0; ts < TT; ++ts) {
        const int p = ts & 1;
        const _Float16* hrd = &hlds[p][0];
        // prefetch next step's xp (full step of latency to land)
        const _Float16* xn = xq + ((ts < TT - 1) ? GG : 0);
        const _Float16 nx = *xn;

        float aLo = 0.f, aHi = 0.f;   // two chains for ILP
#pragma unroll
        for (int cq = 0; cq < 12; ++cq) {     // ks 0..95 from VGPR weights
            half8v hv = *(const half8v*)(&hrd[cq * 8]);
            aLo = FDOT2(SV2(hv, 0, 1), w[cq * 4 + 0], aLo);
            aLo = FDOT2(SV2(hv, 2, 3), w[cq * 4 + 1], aLo);
            aLo = FDOT2(SV2(hv, 4, 5), w[cq * 4 + 2], aLo);
            aLo = FDOT2(SV2(hv, 6, 7), w[cq * 4 + 3], aLo);
        }
#pragma unroll
        for (int cq = 12; cq < 24; ++cq) {    // ks 96..191 from VGPR weights
            half8v hv = *(const half8v*)(&hrd[cq * 8]);
            aHi = FDOT2(SV2(hv, 0, 1), w[cq * 4 + 0], aHi);
            aHi = FDOT2(SV2(hv, 2, 3), w[cq * 4 + 1], aHi);
            aHi = FDOT2(SV2(hv, 4, 5), w[cq * 4 + 2], aHi);
            aHi = FDOT2(SV2(hv, 6, 7), w[cq * 4 + 3], aHi);
        }
#pragma unroll
        for (int grp = 0; grp < 8; ++grp) {   // ks 192..255 from LDS weights
            half8v hv = *(const half8v*)(&hrd[192 + grp * 8]);
            half8v wl = *(const half8v*)(&wlds[grp * 8192 + row * 8]);
            if (grp & 1) {
                aHi = FDOT2(SV2(hv, 0, 1), SV2(wl, 0, 1), aHi);
                aHi = FDOT2(SV2(hv, 2, 3), SV2(wl, 2, 3), aHi);
                aHi = FDOT2(SV2(hv, 4, 5), SV2(wl, 4, 5), aHi);
                aHi = FDOT2(SV2(hv, 6, 7), SV2(wl, 6, 7), aHi);
            } else {
                aLo = FDOT2(SV2(hv, 0, 1), SV2(wl, 0, 1), aLo);
                aLo = FDOT2(SV2(hv, 2, 3), SV2(wl, 2, 3), aLo);
                aLo = FDOT2(SV2(hv, 4, 5), SV2(wl, 4, 5), aLo);
                aLo = FDOT2(SV2(hv, 6, 7), SV2(wl, 6, 7), aLo);
            }
        }

        const float pre = aLo + aHi + (float)x;
        // gather the other 3 gates of this j (all within the wave)
        const float e1 = __shfl_xor(pre, 16, 64);   // gate ^ 1
        const float e2 = __shfl_xor(pre, 32, 64);   // gate ^ 2
        const float e3 = __shfl_xor(pre, 48, 64);   // gate ^ 3
        const float t01 = gb0 ? e1 : pre;
        const float t10 = gb0 ? pre : e1;
        const float t23 = gb0 ? e3 : e2;
        const float t32 = gb0 ? e2 : e3;
        const float gi = gb1 ? t23 : t01;
        const float gf = gb1 ? t32 : t10;
        const float gg = gb1 ? t01 : t23;
        const float go = gb1 ? t10 : t32;

        c = sigm(gf) * c + sigm(gi) * tanh_(gg);
        const float h = sigm(go) * tanh_(c);

        if (gate == 0) {
            hlds[p ^ 1][j] = (_Float16)h;
            if (ts == TT - 1) HF[(size_t)b * HH + j] = h;
        }
        __syncthreads();

        x = nx;
        xq = xn;
    }
}

// ============================================================================
// Kernel 3: backward direction = ONE cell step on x[:, T-1] with h0=c0=0.
// ============================================================================
__global__ __launch_bounds__(256) void lstm_bwd(
    const float* __restrict__ X, const float* __restrict__ Wih,
    const float* __restrict__ bb, float* __restrict__ HB)
{
    __shared__ float xs[II];
    const int b = blockIdx.x, t = threadIdx.x;
    const float* xrow = X + ((size_t)b * TT + (TT - 1)) * II;
    if (t < 75) *(float4*)(&xs[t * 4]) = *(const float4*)(xrow + t * 4);
    __syncthreads();
    if (t < HH) {
        float ai = 0.f, ag = 0.f, ao = 0.f;
        const float4* wi = (const float4*)(Wih + (size_t)t * II);
        const float4* wg = (const float4*)(Wih + (size_t)(t + 512) * II);
        const float4* wo = (const float4*)(Wih + (size_t)(t + 768) * II);
        for (int k4 = 0; k4 < 75; ++k4) {
            float4 xv = *(const float4*)(&xs[k4 * 4]);
            float4 a = wi[k4], g4 = wg[k4], o4 = wo[k4];
            ai += xv.x * a.x + xv.y * a.y + xv.z * a.z + xv.w * a.w;
            ag += xv.x * g4.x + xv.y * g4.y + xv.z * g4.z + xv.w * g4.w;
            ao += xv.x * o4.x + xv.y * o4.y + xv.z * o4.z + xv.w * o4.w;
        }
        ai += bb[t];
        ag += bb[t + 512];
        ao += bb[t + 768];
        const float cg = sigm(ai) * tanh_(ag);
        HB[(size_t)b * HH + t] = sigm(ao) * tanh_(cg);
    }
}

// ============================================================================
// Kernel 4: out[b][jj] = [hf|hb] . W_lin[jj] + b_lin[jj]
// ============================================================================
__global__ __launch_bounds__(256) void final_k(
    const float* __restrict__ HF, const float* __restrict__ HB,
    const float* __restrict__ Wlin, const float* __restrict__ blin,
    float* __restrict__ OUT)
{
    const int t = threadIdx.x;
    const int b = t >> 1, jj = t & 1;
    float acc = blin[jj];
    const float* wf = Wlin + jj * 512;
    const float* wb = Wlin + jj * 512 + 256;
    const float* hf = HF + (size_t)b * HH;
    const float* hb = HB + (size_t)b * HH;
    for (int k = 0; k < HH; k += 4) {
        float4 h4 = *(const float4*)(hf + k);
        float4 w4 = *(const float4*)(wf + k);
        float4 g4 = *(const float4*)(hb + k);
        float4 v4 = *(const float4*)(wb + k);
        acc += h4.x * w4.x + h4.y * w4.y + h4.z * w4.z + h4.w * w4.w;
        acc += g4.x * v4.x + g4.y * v4.y + g4.z * v4.z + g4.w * v4.w;
    }
    OUT[b * 2 + jj] = acc;
}

// ============================================================================
extern "C" void kernel_launch(void* const* d_in, const int* in_sizes, int n_in,
                              void* d_out, int out_size, void* d_ws, size_t ws_size,
                              hipStream_t stream)
{
    const float* x = (const float*)d_in[0];
    const float* Wihf = (const float*)d_in[1];
    const float* Whhf = (const float*)d_in[2];
    const float* bf = (const float*)d_in[3];
    const float* Wihb = (const float*)d_in[4];
    const float* Whhb = (const float*)d_in[5];
    const float* bbv = (const float*)d_in[6];
    const float* Wlin = (const float*)d_in[7];
    const float* blin = (const float*)d_in[8];
    float* out = (float*)d_out;
    (void)Whhb; (void)in_sizes; (void)n_in; (void)out_size;

    // workspace layout: xp fp16 | hf f32 | hb f32 | Xh fp16 | Wh fp16
    const size_t XP_B = (size_t)BB * TT * GG * 2;            // 134,217,728
    const size_t H_B  = (size_t)BB * HH * 4;                 // 131,072
    const size_t XH_B = (size_t)65536 * IIP * 2;             // 41,943,040
    const size_t WH_B = (size_t)GG * IIP * 2;                // 655,360

    _Float16* xp = (_Float16*)d_ws;
    float* hf = (float*)((char*)d_ws + XP_B);
    float* hb = hf + (size_t)BB * HH;
    _Float16* Xh = (_Float16*)((char*)d_ws + XP_B + 2 * H_B);
    _Float16* Wh = Xh + (size_t)65536 * IIP;

    lstm_bwd<<<BB, 256, 0, stream>>>(x, Wihb, bbv, hb);
    if (ws_size >= XP_B + 2 * H_B + XH_B + WH_B) {
        cvt_xw<<<2048, 256, 0, stream>>>(x, Wihf, Xh, Wh);
        gemm_xp_h<<<dim3(GG / 128, (BB * TT) / 128), 256, 0, stream>>>(Xh, Wh, bf, xp);
    } else {
        gemm_xp<<<dim3(GG / 128, (BB * TT) / 128), 256, 0, stream>>>(x, Wihf, bf, xp);
    }
    lstm_fwd<<<BB, 1024, 0, stream>>>(Whhf, xp, hf);
    final_k<<<1, 256, 0, stream>>>(hf, hb, Wlin, blin, out);
}